// Round 23
// baseline (633.574 us; speedup 1.0000x reference)
//
#include <hip/hip_runtime.h>

#define D_DIM 64
#define N_TOK 784
#define C_CH  512

// ---------- K0: order-oracle sniff ----------
__global__ __launch_bounds__(256) void k_sniff(
    const float* __restrict__ p4a, const float* __restrict__ p4b,
    int* __restrict__ flag)
{
    __shared__ float ra[256], rb[256];
    const int tid = threadIdx.x;
    float va = 0.f, vb = 0.f;
    for (int i = tid; i < 4096; i += 256) {
        va = fmaxf(va, fabsf(p4a[i]));
        vb = fmaxf(vb, fabsf(p4b[i]));
    }
    ra[tid] = va; rb[tid] = vb;
    __syncthreads();
    for (int s = 128; s > 0; s >>= 1) {
        if (tid < s) {
            ra[tid] = fmaxf(ra[tid], ra[tid + s]);
            rb[tid] = fmaxf(rb[tid], rb[tid + s]);
        }
        __syncthreads();
    }
    if (tid == 0) *flag = (ra[0] >= rb[0]) ? 1 : 0;
}

// ---------- K1: conv1x1 + bias + pos_emb (R21 version) ----------
__global__ __launch_bounds__(256) void k_conv(
    const float* __restrict__ support, const float* __restrict__ conv_w,
    const float* __restrict__ conv_b, const float* __restrict__ pos_emb,
    float* __restrict__ out_xpe, float* __restrict__ out_x)
{
    __shared__ float S[32][128];
    __shared__ float W[32][68];
    const int b = blockIdx.y;
    const int n0 = blockIdx.x * 128;
    const int tid = threadIdx.x;
    const int tn = tid & 31, td = tid >> 5;
    float acc[4][8];
#pragma unroll
    for (int i = 0; i < 4; ++i)
#pragma unroll
        for (int j = 0; j < 8; ++j) acc[i][j] = 0.f;
    const float* supb = support + (size_t)b * C_CH * N_TOK;
    for (int c0 = 0; c0 < C_CH; c0 += 32) {
#pragma unroll
        for (int j = 0; j < 4; ++j) {
            int q = tid + j * 256;
            int row = q >> 5, c4 = q & 31;
            int nn = n0 + c4 * 4;
            float4 v = make_float4(0.f, 0.f, 0.f, 0.f);
            if (nn < N_TOK) v = *(const float4*)(supb + (size_t)(c0 + row) * N_TOK + nn);
            *(float4*)&S[row][c4 * 4] = v;
        }
#pragma unroll
        for (int j = 0; j < 8; ++j)
            W[tn][td * 8 + j] = conv_w[(td * 8 + j) * C_CH + c0 + tn];
        __syncthreads();
#pragma unroll 8
        for (int cc = 0; cc < 32; ++cc) {
            float4 s4 = *(const float4*)&S[cc][tn * 4];
            float4 wa = *(const float4*)&W[cc][td * 8];
            float4 wb = *(const float4*)&W[cc][td * 8 + 4];
            float sv[4] = {s4.x, s4.y, s4.z, s4.w};
            float wv[8] = {wa.x, wa.y, wa.z, wa.w, wb.x, wb.y, wb.z, wb.w};
#pragma unroll
            for (int i = 0; i < 4; ++i)
#pragma unroll
                for (int j = 0; j < 8; ++j)
                    acc[i][j] = fmaf(sv[i], wv[j], acc[i][j]);
        }
        __syncthreads();
    }
    float bias[8];
#pragma unroll
    for (int j = 0; j < 8; ++j) bias[j] = conv_b[td * 8 + j];
#pragma unroll
    for (int i = 0; i < 4; ++i) {
        int n = n0 + tn * 4 + i;
        if (n >= N_TOK) continue;
        float xv[8], pv[8];
#pragma unroll
        for (int j = 0; j < 8; ++j) {
            xv[j] = acc[i][j] + bias[j];
            pv[j] = xv[j] + pos_emb[(td * 8 + j) * N_TOK + n];
        }
        size_t base = ((size_t)b * N_TOK + n) * D_DIM + td * 8;
        *(float4*)(out_x + base)       = make_float4(xv[0], xv[1], xv[2], xv[3]);
        *(float4*)(out_x + base + 4)   = make_float4(xv[4], xv[5], xv[6], xv[7]);
        *(float4*)(out_xpe + base)     = make_float4(pv[0], pv[1], pv[2], pv[3]);
        *(float4*)(out_xpe + base + 4) = make_float4(pv[4], pv[5], pv[6], pv[7]);
    }
}

// ---------- K2: k = x_pe @ to_k_w^T ----------
__global__ __launch_bounds__(256) void k_makek(
    const float* __restrict__ xpe,
    const float* __restrict__ p4a, const float* __restrict__ p4b,
    const int* __restrict__ flag, float* __restrict__ kout)
{
    const float* to_k_w = (*flag) ? p4b : p4a;
    __shared__ float TW[64][68];
    const int b = blockIdx.y, n0 = blockIdx.x * 128;
    const int tid = threadIdx.x, tn = tid & 31, td = tid >> 5;
#pragma unroll
    for (int j = 0; j < 4; ++j) {
        int q = tid + j * 256;
        int dd = q >> 4, c4 = q & 15;
        *(float4*)&TW[dd][c4 * 4] = *(const float4*)(to_k_w + dd * 64 + c4 * 4);
    }
    __syncthreads();
    float acc[4][8];
#pragma unroll
    for (int i = 0; i < 4; ++i)
#pragma unroll
        for (int j = 0; j < 8; ++j) acc[i][j] = 0.f;
    const float* xb = xpe + (size_t)b * N_TOK * D_DIM;
#pragma unroll 4
    for (int e4 = 0; e4 < 16; ++e4) {
        float4 xv4[4];
#pragma unroll
        for (int i = 0; i < 4; ++i) {
            int n = n0 + tn * 4 + i;
            if (n > 783) n = 783;
            xv4[i] = *(const float4*)(xb + (size_t)n * D_DIM + e4 * 4);
        }
#pragma unroll
        for (int j = 0; j < 8; ++j) {
            float4 w4 = *(const float4*)&TW[td * 8 + j][e4 * 4];
#pragma unroll
            for (int i = 0; i < 4; ++i) {
                acc[i][j] = fmaf(xv4[i].x, w4.x, acc[i][j]);
                acc[i][j] = fmaf(xv4[i].y, w4.y, acc[i][j]);
                acc[i][j] = fmaf(xv4[i].z, w4.z, acc[i][j]);
                acc[i][j] = fmaf(xv4[i].w, w4.w, acc[i][j]);
            }
        }
    }
#pragma unroll
    for (int i = 0; i < 4; ++i) {
        int n = n0 + tn * 4 + i;
        if (n >= N_TOK) continue;
        float* ko = kout + ((size_t)b * N_TOK + n) * D_DIM + td * 8;
        *(float4*)(ko)     = make_float4(acc[i][0], acc[i][1], acc[i][2], acc[i][3]);
        *(float4*)(ko + 4) = make_float4(acc[i][4], acc[i][5], acc[i][6], acc[i][7]);
    }
}

// ---------- K3: ksum[b][d] = sum_n k[b][n][d] (f64) ----------
__global__ __launch_bounds__(256) void k_ksum(
    const float* __restrict__ kf, double* __restrict__ ksum)
{
    __shared__ double part[4][64];
    const int b = blockIdx.x, tid = threadIdx.x;
    const int d = tid & 63, q = tid >> 6;
    const float* kb = kf + (size_t)b * N_TOK * D_DIM + d;
    double s = 0.0;
    for (int n = q; n < N_TOK; n += 4)
        s += (double)kb[(size_t)n * D_DIM];
    part[q][d] = s;
    __syncthreads();
    if (tid < 64)
        ksum[b * 64 + tid] = part[0][tid] + part[1][tid] + part[2][tid] + part[3][tid];
}

// ---------- K4: attn partials — token-split, all 64 slots per block ----------
struct AT {
    float slots[64][68];
    float kch[56][68];
    float attn[64][56];
    float ratio[64];
    double rsum[64];
    double total;
};

__global__ __launch_bounds__(256) void k_attn(
    const float* __restrict__ kf, const float* __restrict__ xf,
    const float* __restrict__ p4a, const float* __restrict__ p4b,
    const float* __restrict__ slots_in, const double* __restrict__ ksum,
    const int* __restrict__ flag,
    float* __restrict__ upd_part, float* __restrict__ srow_part,
    int use_init, int last)
{
    const int alpha = *flag;
    const float* init_slots = alpha ? p4a : p4b;
    __shared__ AT sm;
    const int tid = threadIdx.x;
    const int b  = blockIdx.x / 7;
    const int tq = blockIdx.x % 7;
    const float scale = 0.125f;

    // all 64 slots -> LDS
    for (int q = tid; q < 4096; q += 256) {
        int i = q >> 6, d = q & 63;
        sm.slots[i][d] = use_init ? init_slots[q]
                                  : slots_in[((size_t)b << 12) + q];
    }
    if (tid < 64) {
        const float* srp = use_init ? (init_slots + tid * 64)
                                    : (slots_in + ((size_t)b * 64 + tid) * 64);
        const double* kbs = ksum + b * 64;
        double s = 0.0;
#pragma unroll 8
        for (int d = 0; d < 64; ++d) s += (double)srp[d] * kbs[d];
        sm.rsum[tid] = 0.125 * s;
    }
    __syncthreads();
    if (tid == 0) {
        double t = 0.0;
        for (int i = 0; i < 64; ++i) t += sm.rsum[i];
        sm.total = t;
    }
    __syncthreads();
    if (tid < 64) sm.ratio[tid] = (float)(sm.total / sm.rsum[tid]);
    __syncthreads();

    const int n_l = tid % 56, grp = tid / 56;  // dots: 4 groups x 16 slots (grp<4)
    const int dq = tid & 15, ig = tid >> 4;    // updates: 16x16
    const float* kb = kf + (size_t)b * N_TOK * D_DIM;
    const float* xb = xf + (size_t)b * N_TOK * D_DIM;
    float acc[4][4];
#pragma unroll
    for (int sb = 0; sb < 4; ++sb)
#pragma unroll
        for (int j = 0; j < 4; ++j) acc[sb][j] = 0.f;
    float srow_acc = 0.f;

    for (int c = 0; c < 2; ++c) {
        const int nt0 = tq * 112 + c * 56;
        // stage k chunk
#pragma unroll
        for (int j = 0; j < 4; ++j) {
            int q = tid + j * 256;
            if (q < 896) {
                int n = q >> 4, c4 = q & 15;
                *(float4*)&sm.kch[n][c4 * 4] =
                    *(const float4*)(kb + (size_t)(nt0 + n) * D_DIM + c4 * 4);
            }
        }
        __syncthreads();
        // dots + sigmoid
        if (grp < 4) {
            float kr[64];
#pragma unroll
            for (int e4 = 0; e4 < 16; ++e4)
                *(float4*)&kr[e4 * 4] = *(const float4*)&sm.kch[n_l][e4 * 4];
#pragma unroll
            for (int t = 0; t < 16; ++t) {
                const int il = grp * 16 + t;
                float a = 0.f;
#pragma unroll
                for (int e4 = 0; e4 < 16; ++e4) {
                    float4 s4 = *(const float4*)&sm.slots[il][e4 * 4];
                    a = fmaf(kr[e4 * 4 + 0], s4.x, a);
                    a = fmaf(kr[e4 * 4 + 1], s4.y, a);
                    a = fmaf(kr[e4 * 4 + 2], s4.z, a);
                    a = fmaf(kr[e4 * 4 + 3], s4.w, a);
                }
                float t2 = a * scale * sm.ratio[il];
                sm.attn[il][n_l] = 1.f / (1.f + expf(-t2));
            }
        }
        __syncthreads();
        if (!last) {
            const float* xg = xb + (size_t)nt0 * D_DIM + dq * 4;
#pragma unroll 2
            for (int n = 0; n < 56; ++n) {
                float4 xv = *(const float4*)(xg + (size_t)n * D_DIM);
#pragma unroll
                for (int sb = 0; sb < 4; ++sb) {
                    float a0 = sm.attn[ig + sb * 16][n];
                    acc[sb][0] = fmaf(a0, xv.x, acc[sb][0]);
                    acc[sb][1] = fmaf(a0, xv.y, acc[sb][1]);
                    acc[sb][2] = fmaf(a0, xv.z, acc[sb][2]);
                    acc[sb][3] = fmaf(a0, xv.w, acc[sb][3]);
                }
            }
        } else if (tid < 64) {
            float s = 0.f;
            for (int n = 0; n < 56; ++n) s += sm.attn[tid][n];
            srow_acc += s;
        }
        __syncthreads();
    }

    if (last) {
        if (tid < 64) srow_part[((size_t)(b * 7 + tq)) * 64 + tid] = srow_acc;
        return;
    }
    {
        float* up = upd_part + ((size_t)(b * 7 + tq)) * 4096;
#pragma unroll
        for (int sb = 0; sb < 4; ++sb) {
            int row = ig + sb * 16;
            *(float4*)(up + row * 64 + dq * 4) =
                make_float4(acc[sb][0], acc[sb][1], acc[sb][2], acc[sb][3]);
        }
    }
}

// ---------- K5: GRU — sum partials + gates ----------
struct GT {
    float upd[16][68];
    float slots[16][68];
    float wihc[32][64];
    float whhc[32][64];
    float rz[16][132];
    float inn[16][68];
    float hnn[16][68];
};

__global__ __launch_bounds__(256) void k_gru(
    const float* __restrict__ upd_part,
    const float* __restrict__ p4a, const float* __restrict__ p4b,
    const float* __restrict__ slots_in, float* __restrict__ slots_out,
    const float* __restrict__ p12a, const float* __restrict__ p12b,
    const float* __restrict__ p192a, const float* __restrict__ p192b,
    const int* __restrict__ flag, int use_init)
{
    const int alpha = *flag;
    const float* init_slots = alpha ? p4a : p4b;
    const float* w_ih = alpha ? p12b : p12a;
    const float* w_hh = alpha ? p12a : p12b;
    const float* b_ih = alpha ? p192b : p192a;
    const float* b_hh = alpha ? p192a : p192b;

    __shared__ GT sm;
    const int tid = threadIdx.x;
    const int b = blockIdx.x >> 2;
    const int ilo = (blockIdx.x & 3) * 16;

    for (int q = tid; q < 1024; q += 256) {
        int i = q >> 6, d = q & 63;
        sm.slots[i][d] = use_init ? init_slots[(ilo + i) * 64 + d]
                                  : slots_in[((size_t)b * 64 + ilo + i) * 64 + d];
        double s = 0.0;
        const float* up = upd_part + ((size_t)(b * 7)) * 4096 + (ilo + i) * 64 + d;
#pragma unroll
        for (int tq = 0; tq < 7; ++tq) s += (double)up[tq * 4096];
        sm.upd[i][d] = (float)(s * (1.0 / 64.0));
    }
    __syncthreads();
    for (int gc = 0; gc < 6; ++gc) {
        for (int q = tid; q < 1024; q += 256) {
            int arr = q >> 9, qq = q & 511;
            int gl = qq >> 4, c4 = qq & 15;
            const float* src = arr ? w_hh : w_ih;
            float4 v = *(const float4*)(src + (gc * 32 + gl) * 64 + c4 * 4);
            if (arr) *(float4*)&sm.whhc[gl][c4 * 4] = v;
            else     *(float4*)&sm.wihc[gl][c4 * 4] = v;
        }
        __syncthreads();
        for (int p = tid; p < 512; p += 256) {
            int i = p & 15, gl = p >> 4;
            int g = gc * 32 + gl;
            float aih = 0.f, ahh = 0.f;
#pragma unroll
            for (int e4 = 0; e4 < 16; ++e4) {
                float4 u4 = *(const float4*)&sm.upd[i][e4 * 4];
                float4 s4 = *(const float4*)&sm.slots[i][e4 * 4];
                float4 wi = *(const float4*)&sm.wihc[gl][e4 * 4];
                float4 wh = *(const float4*)&sm.whhc[gl][e4 * 4];
                aih = fmaf(u4.x, wi.x, aih); aih = fmaf(u4.y, wi.y, aih);
                aih = fmaf(u4.z, wi.z, aih); aih = fmaf(u4.w, wi.w, aih);
                ahh = fmaf(s4.x, wh.x, ahh); ahh = fmaf(s4.y, wh.y, ahh);
                ahh = fmaf(s4.z, wh.z, ahh); ahh = fmaf(s4.w, wh.w, ahh);
            }
            aih += b_ih[g]; ahh += b_hh[g];
            if (g < 128) sm.rz[i][g] = aih + ahh;
            else { sm.inn[i][g - 128] = aih; sm.hnn[i][g - 128] = ahh; }
        }
        __syncthreads();
    }
    for (int p = tid; p < 1024; p += 256) {
        int i = p >> 6, d = p & 63;
        float r = 1.f / (1.f + expf(-sm.rz[i][d]));
        float z = 1.f / (1.f + expf(-sm.rz[i][64 + d]));
        float nn2 = tanhf(sm.inn[i][d] + r * sm.hnn[i][d]);
        float h = sm.slots[i][d];
        slots_out[((size_t)b * 64 + ilo + i) * 64 + d] = (1.f - z) * nn2 + z * h;
    }
}

// ---------- K6: scores (sum srow partials) + argmax -> created ----------
__global__ __launch_bounds__(64) void k_final2(
    const float* __restrict__ srow_part,
    const float* __restrict__ p4a, const float* __restrict__ p4b,
    const int* __restrict__ flag, float* __restrict__ outp)
{
    const float* init_slots = (*flag) ? p4a : p4b;
    const int way = blockIdx.x, tid = threadIdx.x;
    __shared__ float sc[64];
    __shared__ int bidx;
    {
        double s = 0.0;
        for (int shot = 0; shot < 8; ++shot)
            for (int tq = 0; tq < 7; ++tq)
                s += (double)srow_part[((size_t)((way * 8 + shot) * 7 + tq)) * 64 + tid];
        sc[tid] = (float)s;
    }
    __syncthreads();
    if (tid == 0) {
        float best = sc[0]; int bi = 0;
        for (int i = 1; i < 64; ++i)
            if (sc[i] > best) { best = sc[i]; bi = i; }
        bidx = bi;
    }
    __syncthreads();
    outp[way * 848 + tid] = init_slots[bidx * 64 + tid];
}

// ---------- K7: avg_feature from out_x ----------
__global__ __launch_bounds__(256) void k_avg_x(
    const float* __restrict__ xf, float* __restrict__ outp)
{
    const int way = blockIdx.y, ch = blockIdx.x, tid = threadIdx.x;
    const int w = tid >> 6, lane = tid & 63;
    for (int t = w; t < 112; t += 4) {
        int n = ch * 112 + t;
        double s = 0.0;
#pragma unroll
        for (int shot = 0; shot < 8; ++shot)
            s += (double)xf[((size_t)(way * 8 + shot) * N_TOK + n) * D_DIM + lane];
        s += __shfl_xor(s, 1);  s += __shfl_xor(s, 2);  s += __shfl_xor(s, 4);
        s += __shfl_xor(s, 8);  s += __shfl_xor(s, 16); s += __shfl_xor(s, 32);
        if (lane == 0) outp[way * 848 + 64 + n] = (float)(s * (1.0 / 512.0));
    }
}

extern "C" void kernel_launch(void* const* d_in, const int* in_sizes, int n_in,
                              void* d_out, int out_size, void* d_ws, size_t ws_size,
                              hipStream_t stream)
{
    int iS = 0, iW = 1, iB = 2, iP = 3;
    int i4a = -1, i4b = -1, i12a = -1, i12b = -1, i192a = -1, i192b = -1;
    for (int i = 0; i < n_in; ++i) {
        if (in_sizes[i] == 51380224) iS = i;
        else if (in_sizes[i] == 32768) iW = i;
        else if (in_sizes[i] == 64) iB = i;
        else if (in_sizes[i] == 50176) iP = i;
        else if (in_sizes[i] == 4096)  { if (i4a < 0) i4a = i; else i4b = i; }
        else if (in_sizes[i] == 12288) { if (i12a < 0) i12a = i; else i12b = i; }
        else if (in_sizes[i] == 192)   { if (i192a < 0) i192a = i; else i192b = i; }
    }
    if (i4b < 0)  { i4a = 4; i4b = 9; }
    if (i12b < 0) { i12a = 5; i12b = 6; }
    if (i192b < 0){ i192a = 7; i192b = 8; }

    const float* support = (const float*)d_in[iS];
    const float* conv_w  = (const float*)d_in[iW];
    const float* conv_b  = (const float*)d_in[iB];
    const float* pos_emb = (const float*)d_in[iP];
    const float* p4a   = (const float*)d_in[i4a];
    const float* p4b   = (const float*)d_in[i4b];
    const float* p12a  = (const float*)d_in[i12a];
    const float* p12b  = (const float*)d_in[i12b];
    const float* p192a = (const float*)d_in[i192a];
    const float* p192b = (const float*)d_in[i192b];

    float* out     = (float*)d_out;
    float* out_xpe = out + 13568;
    float* out_x   = out + 13568 + 6422528;

    char* ws = (char*)d_ws;
    float*  kf        = (float*)ws;                       // 25,690,112 B
    float*  slots_a   = (float*)(ws + 25690112);          //  2,097,152 B
    float*  slots_b   = (float*)(ws + 27787264);          //  2,097,152 B
    double* ksum      = (double*)(ws + 29884416);         //     65,536 B
    float*  srow_part = (float*)(ws + 29949952);          //    229,376 B
    float*  upd_part  = (float*)(ws + 30179328);          // 14,680,064 B
    int*    flag      = (int*)(ws + 44859392);            //          4 B

    k_sniff<<<1, 256, 0, stream>>>(p4a, p4b, flag);

    dim3 gconv(7, 128);
    k_conv<<<gconv, 256, 0, stream>>>(support, conv_w, conv_b, pos_emb, out_xpe, out_x);
    k_makek<<<gconv, 256, 0, stream>>>(out_xpe, p4a, p4b, flag, kf);
    k_ksum<<<128, 256, 0, stream>>>(kf, ksum);

    // iter 1
    k_attn<<<896, 256, 0, stream>>>(kf, out_x, p4a, p4b, slots_a, ksum, flag,
                                    upd_part, srow_part, 1, 0);
    k_gru<<<512, 256, 0, stream>>>(upd_part, p4a, p4b, slots_a, slots_a,
                                   p12a, p12b, p192a, p192b, flag, 1);
    // iter 2
    k_attn<<<896, 256, 0, stream>>>(kf, out_x, p4a, p4b, slots_a, ksum, flag,
                                    upd_part, srow_part, 0, 0);
    k_gru<<<512, 256, 0, stream>>>(upd_part, p4a, p4b, slots_a, slots_b,
                                   p12a, p12b, p192a, p192b, flag, 0);
    // iter 3 (scores only)
    k_attn<<<896, 256, 0, stream>>>(kf, out_x, p4a, p4b, slots_b, ksum, flag,
                                    upd_part, srow_part, 0, 1);

    k_final2<<<16, 64, 0, stream>>>(srow_part, p4a, p4b, flag, out);
    dim3 gavg(7, 16);
    k_avg_x<<<gavg, 256, 0, stream>>>(out_x, out);
}